// Round 4
// baseline (1732.880 us; speedup 1.0000x reference)
//
#include <hip/hip_runtime.h>
#include <math.h>

#define V_  10000
#define E_  256
#define H_  512
#define B_  8
#define S_  512
#define G4H 2048   // 4*H
#define NPAD 10112 // 79*128, padded N for k_out

typedef __attribute__((ext_vector_type(8))) short bf16x8;
typedef __attribute__((ext_vector_type(4))) float f32x4;

__device__ __forceinline__ float sigmoidf_(float x) { return 1.f / (1.f + expf(-x)); }
__device__ __forceinline__ unsigned short f2bf(float x) {
  unsigned u = __float_as_uint(x);
  return (unsigned short)((u + 0x7fffu + ((u >> 16) & 1u)) >> 16);
}
__device__ __forceinline__ float bf2f(unsigned short h) {
  return __uint_as_float(((unsigned)h) << 16);
}
// fast activations on the serial critical path (clamped; exact at saturation)
__device__ __forceinline__ float fsig(float x) {
  x = fminf(fmaxf(x, -30.f), 30.f);
  return __builtin_amdgcn_rcpf(1.f + __builtin_amdgcn_exp2f(-1.44269504f * x));
}
__device__ __forceinline__ float ftanh(float x) {
  x = fminf(fmaxf(x, -9.f), 9.f);
  float E = __builtin_amdgcn_exp2f(2.88539008f * x);  // e^{2x}
  return (E - 1.f) * __builtin_amdgcn_rcpf(E + 1.f);
}

#define GLOAD_LDS16(gsrc, ldst)                                                       \
  __builtin_amdgcn_global_load_lds((const __attribute__((address_space(1))) unsigned*)(gsrc), \
                                   (__attribute__((address_space(3))) unsigned*)(ldst), 16, 0, 0)

// ---------------------------------------------------------------------------
// K1: pre[m][j] = embed[tok(m)][:] @ w_ih[:, j] + bias[j],  m = s*8+b  (fp32)
// ---------------------------------------------------------------------------
__global__ __launch_bounds__(256, 4) void k_pre(
    const int* __restrict__ tokens, const float* __restrict__ embed,
    const float* __restrict__ w_ih, const float* __restrict__ bias,
    float* __restrict__ pre)
{
  __shared__ float A_lds[64 * 36];
  __shared__ float B_lds[32 * 64];
  __shared__ int   tok_lds[64];
  const int t  = threadIdx.x;
  const int m0 = blockIdx.x * 64;
  const int j0 = blockIdx.y * 64;
  if (t < 64) {
    int m = m0 + t;
    int s = m >> 3, b = m & 7;
    tok_lds[t] = tokens[b * S_ + s];
  }
  __syncthreads();
  const int tx = t & 15, ty = t >> 4;
  const int r_st = t >> 2, q_st = t & 3;
  const int kk_st = t >> 3, q2_st = t & 7;
  float acc[4][4] = {};
  for (int kt = 0; kt < E_; kt += 32) {
    {
      int tok = tok_lds[r_st];
      const float4* src = (const float4*)(embed + (size_t)tok * E_ + kt);
      float4 v0 = src[q_st];
      float4 v1 = src[q_st + 4];
      *(float4*)&A_lds[r_st * 36 + q_st * 4]       = v0;
      *(float4*)&A_lds[r_st * 36 + (q_st + 4) * 4] = v1;
    }
    {
      const float4* src = (const float4*)(w_ih + (size_t)(kt + kk_st) * G4H + j0);
      float4 v0 = src[q2_st];
      float4 v1 = src[q2_st + 8];
      *(float4*)&B_lds[kk_st * 64 + q2_st * 4]       = v0;
      *(float4*)&B_lds[kk_st * 64 + (q2_st + 8) * 4] = v1;
    }
    __syncthreads();
#pragma unroll
    for (int kkg = 0; kkg < 8; ++kkg) {
      float a_[4][4], b_[4][4];
#pragma unroll
      for (int i = 0; i < 4; ++i) {
        float4 av = *(const float4*)&A_lds[(ty * 4 + i) * 36 + kkg * 4];
        a_[i][0] = av.x; a_[i][1] = av.y; a_[i][2] = av.z; a_[i][3] = av.w;
      }
#pragma unroll
      for (int dk = 0; dk < 4; ++dk) {
        float4 bv = *(const float4*)&B_lds[(kkg * 4 + dk) * 64 + tx * 4];
        b_[dk][0] = bv.x; b_[dk][1] = bv.y; b_[dk][2] = bv.z; b_[dk][3] = bv.w;
      }
#pragma unroll
      for (int i = 0; i < 4; ++i)
#pragma unroll
        for (int dk = 0; dk < 4; ++dk)
#pragma unroll
          for (int j = 0; j < 4; ++j)
            acc[i][j] += a_[i][dk] * b_[dk][j];
    }
    __syncthreads();
  }
  const int j = j0 + tx * 4;
  float4 bi = *(const float4*)(bias + j);
#pragma unroll
  for (int i = 0; i < 4; ++i) {
    int m = m0 + ty * 4 + i;
    float4 o;
    o.x = acc[i][0] + bi.x; o.y = acc[i][1] + bi.y;
    o.z = acc[i][2] + bi.z; o.w = acc[i][3] + bi.w;
    *(float4*)&pre[(size_t)m * G4H + j] = o;
  }
}

// ---------------------------------------------------------------------------
// K-conv: w_out [512][10000] fp32 -> transposed bf16 hi/lo [NPAD][512].
// ---------------------------------------------------------------------------
__global__ __launch_bounds__(256, 4) void k_wconv(
    const float* __restrict__ w_out,
    unsigned short* __restrict__ wT_hi, unsigned short* __restrict__ wT_lo)
{
  __shared__ float tile[64][65];
  const int t  = threadIdx.x;
  const int n0 = blockIdx.x * 64;
  const int k0 = blockIdx.y * 64;
  const int cn = (t & 15) * 4, rk = t >> 4;
#pragma unroll
  for (int p = 0; p < 4; ++p) {
    int k = k0 + rk + p * 16;
    int n = n0 + cn;
    float v[4];
    if (n + 3 < V_) {
      float4 x = *(const float4*)(w_out + (size_t)k * V_ + n);
      v[0] = x.x; v[1] = x.y; v[2] = x.z; v[3] = x.w;
    } else {
#pragma unroll
      for (int j = 0; j < 4; ++j) v[j] = (n + j < V_) ? w_out[(size_t)k * V_ + n + j] : 0.f;
    }
#pragma unroll
    for (int j = 0; j < 4; ++j) tile[rk + p * 16][cn + j] = v[j];
  }
  __syncthreads();
  const int n_l = t >> 2, kq = t & 3;
  unsigned short hib[16], lob[16];
#pragma unroll
  for (int j = 0; j < 16; ++j) {
    float x = tile[kq * 16 + j][n_l];
    unsigned short h = f2bf(x);
    hib[j] = h;
    lob[j] = f2bf(x - bf2f(h));
  }
  size_t base = (size_t)(n0 + n_l) * 512 + k0 + kq * 16;
#pragma unroll
  for (int q = 0; q < 4; ++q) {
    *(ushort4*)&wT_hi[base + q * 4] = *(ushort4*)&hib[q * 4];
    *(ushort4*)&wT_lo[base + q * 4] = *(ushort4*)&lob[q * 4];
  }
}

// ---------------------------------------------------------------------------
// K2 (latency-trimmed): 8 clusters (cluster = bid&7 -> XCD-local if round-robin
// mapping holds) x 16 WGs x 512 threads. Per wave: 4 units x 4 gates, k split
// over 16 lane-groups (kq = lane>>2, 32 k each). Per step: poll own h elem ->
// parity-double-buffered padded h_lds -> ONE syncthreads -> b128 h reads +
// 128 reg FMAs -> in-wave butterfly over kq -> act on kq==0 lanes (fast
// exp2/rcp) -> release-store packed {seq,h}. No partials LDS, no 2nd sync.
// Race-safety: buffer p overwrite at step s+2 is gated via producers' polls
// on every wave's step-s reads (wave lockstep: reads precede act store).
// ---------------------------------------------------------------------------
__global__ __launch_bounds__(512, 2) void k_rec(
    const float* __restrict__ pre, const float* __restrict__ w_hh,
    unsigned long long* __restrict__ hbuf,  // [2][B][H] u64, zeroed
    unsigned short* __restrict__ hs_hi,     // [S*B][H] bf16
    unsigned short* __restrict__ hs_lo,     // [S*B][H] bf16
    float* __restrict__ out_tail)           // h_T [B][H] then c_T [B][H]
{
  __shared__ float4 h4_lds[2 * 144];  // [parity][16 chunks][9 xfloat4] (pad 36 floats)
  float* hf = (float*)h4_lds;
  const int t  = threadIdx.x;
  const int c  = blockIdx.x & 7;   // batch/cluster
  const int r  = blockIdx.x >> 3;  // rank 0..15
  const int u0 = r * 32;
  const int w  = t >> 6, l = t & 63;
  const int ul = l & 3, kq = l >> 2;
  const int u  = u0 + w * 4 + ul;          // this lane's unit
  const int pw = (t >> 5) * 36 + (t & 31); // padded write slot for polled elem

  // weights: unit u, k-chunk kq*32..+32, 4 gates -> 128 VGPRs
  float4 wreg[32];
  const int k0 = kq * 32;
#pragma unroll
  for (int i = 0; i < 32; ++i) {
    const float* wr = w_hh + (size_t)(k0 + i) * G4H + u;
    wreg[i] = make_float4(wr[0], wr[512], wr[1024], wr[1536]);
  }
  const bool is_act = (kq == 0);
  float c_state = 0.f;

  for (int s = 0; s < S_; ++s) {
    const int par = s & 1;
    float p0 = 0.f, p1 = 0.f, p2 = 0.f, p3 = 0.f;
    if (is_act) {  // prefetch pre (L2-resident), consumed after butterfly
      const float* pp = pre + ((size_t)(s * B_ + c)) * G4H + u;
      p0 = pp[0]; p1 = pp[512]; p2 = pp[1024]; p3 = pp[1536];
    }
    {  // poll own unit's packed {seq|h}
      const unsigned long long* src = hbuf + ((par * B_ + c) * H_) + t;
      unsigned long long v = __hip_atomic_load(src, __ATOMIC_RELAXED, __HIP_MEMORY_SCOPE_AGENT);
      while ((unsigned)(v >> 32) != (unsigned)s)
        v = __hip_atomic_load(src, __ATOMIC_RELAXED, __HIP_MEMORY_SCOPE_AGENT);
      hf[par * 576 + pw] = __uint_as_float((unsigned)v);
    }
    __syncthreads();  // publish h_lds (only barrier in the step)
    float a0 = 0.f, a1 = 0.f, a2 = 0.f, a3 = 0.f;
    const float4* h4 = h4_lds + par * 144 + kq * 9;
#pragma unroll
    for (int i4 = 0; i4 < 8; ++i4) {
      float4 hv = h4[i4];
      float4 w0 = wreg[i4 * 4 + 0], w1 = wreg[i4 * 4 + 1];
      float4 w2 = wreg[i4 * 4 + 2], w3 = wreg[i4 * 4 + 3];
      a0 += w0.x * hv.x + w1.x * hv.y + w2.x * hv.z + w3.x * hv.w;
      a1 += w0.y * hv.x + w1.y * hv.y + w2.y * hv.z + w3.y * hv.w;
      a2 += w0.z * hv.x + w1.z * hv.y + w2.z * hv.z + w3.z * hv.w;
      a3 += w0.w * hv.x + w1.w * hv.y + w2.w * hv.z + w3.w * hv.w;
    }
#pragma unroll
    for (int mask = 4; mask <= 32; mask <<= 1) {  // butterfly over kq bits
      a0 += __shfl_xor(a0, mask, 64);
      a1 += __shfl_xor(a1, mask, 64);
      a2 += __shfl_xor(a2, mask, 64);
      a3 += __shfl_xor(a3, mask, 64);
    }
    if (is_act) {
      float gi = a0 + p0, gf = a1 + p1, gg = a2 + p2, go = a3 + p3;
      float ig = fsig(gi), fg = fsig(gf), gt = ftanh(gg), og = fsig(go);
      c_state = fg * c_state + ig * gt;
      float h = og * ftanh(c_state);
      // release store FIRST (critical path), bookkeeping after
      unsigned long long pk = ((unsigned long long)(unsigned)(s + 1) << 32)
                            | (unsigned long long)__float_as_uint(h);
      __hip_atomic_store(hbuf + ((((s + 1) & 1) * B_ + c) * H_) + u, pk,
                         __ATOMIC_RELAXED, __HIP_MEMORY_SCOPE_AGENT);
      size_t hidx = ((size_t)(s * B_ + c)) * H_ + u;
      unsigned short hh = f2bf(h);
      hs_hi[hidx] = hh;
      hs_lo[hidx] = f2bf(h - bf2f(hh));
      if (s == S_ - 1) {
        out_tail[c * H_ + u]           = h;
        out_tail[B_ * H_ + c * H_ + u] = c_state;
      }
    }
  }
}

// ---------------------------------------------------------------------------
// K3 (MFMA): out = log_softmax_b(relu(hs @ w_out + b_out)).  (unchanged)
// ---------------------------------------------------------------------------
__global__ __launch_bounds__(256, 2) void k_out(
    const unsigned short* __restrict__ hs_hi, const unsigned short* __restrict__ hs_lo,
    const unsigned short* __restrict__ wT_hi, const unsigned short* __restrict__ wT_lo,
    const float* __restrict__ b_out, float* __restrict__ out)
{
  __shared__ unsigned short lds[4 * 128 * 64];  // A_hi | A_lo | B_hi | B_lo, 64 KB
  char* ldsc = (char*)lds;
  const int t  = threadIdx.x;
  const int w  = t >> 6, l = t & 63;
  const int m0 = blockIdx.x * 128;
  const int n0 = blockIdx.y * 128;
  const int wm = w >> 1, wn = w & 1;
  const int lm = l & 15, lq = l >> 4;

  f32x4 acc[4][4];
#pragma unroll
  for (int fm = 0; fm < 4; ++fm)
#pragma unroll
    for (int fn = 0; fn < 4; ++fn) acc[fm][fn] = (f32x4){0.f, 0.f, 0.f, 0.f};

  for (int kt = 0; kt < H_; kt += 64) {
#pragma unroll
    for (int i = 0; i < 4; ++i) {
      int o   = i * 4096 + w * 1024 + l * 16;
      int r   = o >> 7;
      int c16 = (o >> 4) & 7;
      int cs  = c16 ^ (r & 7);
      const unsigned short* sAh = hs_hi + (size_t)(m0 + r) * 512 + kt + cs * 8;
      const unsigned short* sAl = hs_lo + (size_t)(m0 + r) * 512 + kt + cs * 8;
      const unsigned short* sBh = wT_hi + (size_t)(n0 + r) * 512 + kt + cs * 8;
      const unsigned short* sBl = wT_lo + (size_t)(n0 + r) * 512 + kt + cs * 8;
      GLOAD_LDS16(sAh, ldsc + 0     + i * 4096 + w * 1024);
      GLOAD_LDS16(sAl, ldsc + 16384 + i * 4096 + w * 1024);
      GLOAD_LDS16(sBh, ldsc + 32768 + i * 4096 + w * 1024);
      GLOAD_LDS16(sBl, ldsc + 49152 + i * 4096 + w * 1024);
    }
    __syncthreads();
#pragma unroll
    for (int ks = 0; ks < 2; ++ks) {
      bf16x8 ah[4], al[4], bh[4], bl[4];
#pragma unroll
      for (int f = 0; f < 4; ++f) {
        int ra = wm * 64 + f * 16 + lm;
        int ca = (ks * 4 + lq) ^ (ra & 7);
        ah[f] = *(const bf16x8*)(ldsc + 0     + ra * 128 + ca * 16);
        al[f] = *(const bf16x8*)(ldsc + 16384 + ra * 128 + ca * 16);
        int rb = wn * 64 + f * 16 + lm;
        int cb = (ks * 4 + lq) ^ (rb & 7);
        bh[f] = *(const bf16x8*)(ldsc + 32768 + rb * 128 + cb * 16);
        bl[f] = *(const bf16x8*)(ldsc + 49152 + rb * 128 + cb * 16);
      }
#pragma unroll
      for (int fm = 0; fm < 4; ++fm)
#pragma unroll
        for (int fn = 0; fn < 4; ++fn) {
          acc[fm][fn] = __builtin_amdgcn_mfma_f32_16x16x32_bf16(ah[fm], bh[fn], acc[fm][fn], 0, 0, 0);
          acc[fm][fn] = __builtin_amdgcn_mfma_f32_16x16x32_bf16(ah[fm], bl[fn], acc[fm][fn], 0, 0, 0);
          acc[fm][fn] = __builtin_amdgcn_mfma_f32_16x16x32_bf16(al[fm], bh[fn], acc[fm][fn], 0, 0, 0);
        }
    }
    __syncthreads();
  }

#pragma unroll
  for (int fn = 0; fn < 4; ++fn) {
    const int n = n0 + wn * 64 + fn * 16 + lm;
    const float bo = (n < V_) ? b_out[n] : 0.f;
#pragma unroll
    for (int fm = 0; fm < 4; ++fm) {
      float v[4];
#pragma unroll
      for (int rg = 0; rg < 4; ++rg) v[rg] = fmaxf(acc[fm][fn][rg] + bo, 0.f);
      float mx = fmaxf(fmaxf(v[0], v[1]), fmaxf(v[2], v[3]));
      float gm = fmaxf(mx, __shfl_xor(mx, 16, 64));
      float ss = expf(v[0] - gm) + expf(v[1] - gm) + expf(v[2] - gm) + expf(v[3] - gm);
      float lse = gm + logf(ss + __shfl_xor(ss, 16, 64));
      if (n < V_) {
#pragma unroll
        for (int rg = 0; rg < 4; ++rg) {
          int m = m0 + wm * 64 + fm * 16 + lq * 4 + rg;
          int s = m >> 3, b = m & 7;
          out[(size_t)b * ((size_t)S_ * V_) + (size_t)s * V_ + n] = v[rg] - lse;
        }
      }
    }
  }
}

// ---------------------------------------------------------------------------
extern "C" void kernel_launch(void* const* d_in, const int* in_sizes, int n_in,
                              void* d_out, int out_size, void* d_ws, size_t ws_size,
                              hipStream_t stream) {
  const int*   tokens = (const int*)d_in[0];
  const float* embed  = (const float*)d_in[1];
  const float* w_ih   = (const float*)d_in[2];
  const float* w_hh   = (const float*)d_in[3];
  const float* bias   = (const float*)d_in[4];
  const float* w_out  = (const float*)d_in[5];
  const float* b_out  = (const float*)d_in[6];
  float* out = (float*)d_out;

  char* ws = (char*)d_ws;
  float*              pre   = (float*)(ws);                         // 33,554,432 B
  unsigned short*     hs_hi = (unsigned short*)(ws + 33554432);     //  4,194,304 B
  unsigned short*     hs_lo = (unsigned short*)(ws + 37748736);     //  4,194,304 B
  unsigned short*     wT_hi = (unsigned short*)(ws + 41943040);     // 10,354,688 B
  unsigned short*     wT_lo = (unsigned short*)(ws + 52297728);     // 10,354,688 B
  unsigned long long* hbuf  = (unsigned long long*)(ws + 62652416); //     65,536 B

  hipMemsetAsync(hbuf, 0, 2 * B_ * H_ * sizeof(unsigned long long), stream);

  k_wconv<<<dim3(158, 8), 256, 0, stream>>>(w_out, wT_hi, wT_lo);
  k_pre<<<dim3(64, 32), 256, 0, stream>>>(tokens, embed, w_ih, bias, pre);
  k_rec<<<dim3(128), 512, 0, stream>>>(pre, w_hh, hbuf, hs_hi, hs_lo,
                                       out + (size_t)B_ * S_ * V_);
  k_out<<<dim3(32, 79), 256, 0, stream>>>(hs_hi, hs_lo, wT_hi, wT_lo, b_out, out);
}

// Round 6
// 1098.704 us; speedup vs baseline: 1.5772x; 1.5772x over previous
//
#include <hip/hip_runtime.h>
#include <math.h>

#define V_  10000
#define E_  256
#define H_  512
#define B_  8
#define S_  512
#define G4H 2048   // 4*H
#define NPAD 10112 // 79*128, padded N for k_out

typedef __attribute__((ext_vector_type(8))) short bf16x8;
typedef __attribute__((ext_vector_type(4))) float f32x4;

__device__ __forceinline__ unsigned short f2bf(float x) {
  unsigned u = __float_as_uint(x);
  return (unsigned short)((u + 0x7fffu + ((u >> 16) & 1u)) >> 16);
}
__device__ __forceinline__ float bf2f(unsigned short h) {
  return __uint_as_float(((unsigned)h) << 16);
}
// fast activations on the serial critical path (clamped; exact at saturation)
__device__ __forceinline__ float fsig(float x) {
  x = fminf(fmaxf(x, -30.f), 30.f);
  return __builtin_amdgcn_rcpf(1.f + __builtin_amdgcn_exp2f(-1.44269504f * x));
}
__device__ __forceinline__ float ftanh(float x) {
  x = fminf(fmaxf(x, -9.f), 9.f);
  float E = __builtin_amdgcn_exp2f(2.88539008f * x);  // e^{2x}
  return (E - 1.f) * __builtin_amdgcn_rcpf(E + 1.f);
}

#define GLOAD_LDS16(gsrc, ldst)                                                       \
  __builtin_amdgcn_global_load_lds((const __attribute__((address_space(1))) unsigned*)(gsrc), \
                                   (__attribute__((address_space(3))) unsigned*)(ldst), 16, 0, 0)

// ---------------------------------------------------------------------------
// K1: pre[m][j] = embed[tok(m)][:] @ w_ih[:, j] + bias[j],  m = s*8+b  (fp32)
// ---------------------------------------------------------------------------
__global__ __launch_bounds__(256, 4) void k_pre(
    const int* __restrict__ tokens, const float* __restrict__ embed,
    const float* __restrict__ w_ih, const float* __restrict__ bias,
    float* __restrict__ pre)
{
  __shared__ float A_lds[64 * 36];
  __shared__ float B_lds[32 * 64];
  __shared__ int   tok_lds[64];
  const int t  = threadIdx.x;
  const int m0 = blockIdx.x * 64;
  const int j0 = blockIdx.y * 64;
  if (t < 64) {
    int m = m0 + t;
    int s = m >> 3, b = m & 7;
    tok_lds[t] = tokens[b * S_ + s];
  }
  __syncthreads();
  const int tx = t & 15, ty = t >> 4;
  const int r_st = t >> 2, q_st = t & 3;
  const int kk_st = t >> 3, q2_st = t & 7;
  float acc[4][4] = {};
  for (int kt = 0; kt < E_; kt += 32) {
    {
      int tok = tok_lds[r_st];
      const float4* src = (const float4*)(embed + (size_t)tok * E_ + kt);
      float4 v0 = src[q_st];
      float4 v1 = src[q_st + 4];
      *(float4*)&A_lds[r_st * 36 + q_st * 4]       = v0;
      *(float4*)&A_lds[r_st * 36 + (q_st + 4) * 4] = v1;
    }
    {
      const float4* src = (const float4*)(w_ih + (size_t)(kt + kk_st) * G4H + j0);
      float4 v0 = src[q2_st];
      float4 v1 = src[q2_st + 8];
      *(float4*)&B_lds[kk_st * 64 + q2_st * 4]       = v0;
      *(float4*)&B_lds[kk_st * 64 + (q2_st + 8) * 4] = v1;
    }
    __syncthreads();
#pragma unroll
    for (int kkg = 0; kkg < 8; ++kkg) {
      float a_[4][4], b_[4][4];
#pragma unroll
      for (int i = 0; i < 4; ++i) {
        float4 av = *(const float4*)&A_lds[(ty * 4 + i) * 36 + kkg * 4];
        a_[i][0] = av.x; a_[i][1] = av.y; a_[i][2] = av.z; a_[i][3] = av.w;
      }
#pragma unroll
      for (int dk = 0; dk < 4; ++dk) {
        float4 bv = *(const float4*)&B_lds[(kkg * 4 + dk) * 64 + tx * 4];
        b_[dk][0] = bv.x; b_[dk][1] = bv.y; b_[dk][2] = bv.z; b_[dk][3] = bv.w;
      }
#pragma unroll
      for (int i = 0; i < 4; ++i)
#pragma unroll
        for (int dk = 0; dk < 4; ++dk)
#pragma unroll
          for (int j = 0; j < 4; ++j)
            acc[i][j] += a_[i][dk] * b_[dk][j];
    }
    __syncthreads();
  }
  const int j = j0 + tx * 4;
  float4 bi = *(const float4*)(bias + j);
#pragma unroll
  for (int i = 0; i < 4; ++i) {
    int m = m0 + ty * 4 + i;
    float4 o;
    o.x = acc[i][0] + bi.x; o.y = acc[i][1] + bi.y;
    o.z = acc[i][2] + bi.z; o.w = acc[i][3] + bi.w;
    *(float4*)&pre[(size_t)m * G4H + j] = o;
  }
}

// ---------------------------------------------------------------------------
// K-conv: w_out [512][10000] fp32 -> transposed bf16 hi/lo [NPAD][512].
// ---------------------------------------------------------------------------
__global__ __launch_bounds__(256, 4) void k_wconv(
    const float* __restrict__ w_out,
    unsigned short* __restrict__ wT_hi, unsigned short* __restrict__ wT_lo)
{
  __shared__ float tile[64][65];
  const int t  = threadIdx.x;
  const int n0 = blockIdx.x * 64;
  const int k0 = blockIdx.y * 64;
  const int cn = (t & 15) * 4, rk = t >> 4;
#pragma unroll
  for (int p = 0; p < 4; ++p) {
    int k = k0 + rk + p * 16;
    int n = n0 + cn;
    float v[4];
    if (n + 3 < V_) {
      float4 x = *(const float4*)(w_out + (size_t)k * V_ + n);
      v[0] = x.x; v[1] = x.y; v[2] = x.z; v[3] = x.w;
    } else {
#pragma unroll
      for (int j = 0; j < 4; ++j) v[j] = (n + j < V_) ? w_out[(size_t)k * V_ + n + j] : 0.f;
    }
#pragma unroll
    for (int j = 0; j < 4; ++j) tile[rk + p * 16][cn + j] = v[j];
  }
  __syncthreads();
  const int n_l = t >> 2, kq = t & 3;
  unsigned short hib[16], lob[16];
#pragma unroll
  for (int j = 0; j < 16; ++j) {
    float x = tile[kq * 16 + j][n_l];
    unsigned short h = f2bf(x);
    hib[j] = h;
    lob[j] = f2bf(x - bf2f(h));
  }
  size_t base = (size_t)(n0 + n_l) * 512 + k0 + kq * 16;
#pragma unroll
  for (int q = 0; q < 4; ++q) {
    *(ushort4*)&wT_hi[base + q * 4] = *(ushort4*)&hib[q * 4];
    *(ushort4*)&wT_lo[base + q * 4] = *(ushort4*)&lob[q * 4];
  }
}

// ---------------------------------------------------------------------------
// K2: EXACT round-3 structure (849 us known-good: spread clusters c=bid>>4,
// wave-local FMA with no post-poll sync, 2-sync LDS reduce) + three safe
// deltas: fast act (exp2/rcp), release-store-first, s_setprio around act.
// ---------------------------------------------------------------------------
__global__ __launch_bounds__(512, 2) void k_rec(
    const float* __restrict__ pre, const float* __restrict__ w_hh,
    unsigned long long* __restrict__ hbuf,  // [2][B][H] u64, zeroed
    unsigned short* __restrict__ hs_hi,     // [S*B][H] bf16
    unsigned short* __restrict__ hs_lo,     // [S*B][H] bf16
    float* __restrict__ out_tail)           // h_T [B][H] then c_T [B][H]
{
  __shared__ float h_lds[H_];
  __shared__ float partials[16 * 32 * 4];
  __shared__ float gates_lds[32 * 4];

  const int t   = threadIdx.x;
  const int bid = blockIdx.x;
  const int c   = bid >> 4;   // batch/cluster (spread over XCDs)
  const int r   = bid & 15;   // rank within cluster
  const int u0  = r * 32;
  const int u_l = t & 31;
  const int kq  = t >> 5;
  const int k0  = kq * 32;
  const int ug  = u0 + u_l;

  float4 wreg[32];
#pragma unroll
  for (int i = 0; i < 32; ++i) {
    const float* wr = w_hh + (size_t)(k0 + i) * G4H + ug;
    wreg[i] = make_float4(wr[0], wr[512], wr[1024], wr[1536]);
  }

  const bool is_act = (t < 32);
  float c_state = 0.f;

  for (int s = 0; s < S_; ++s) {
    float p0 = 0.f, p1 = 0.f, p2 = 0.f, p3 = 0.f;
    if (is_act) {  // prefetch pre, overlaps the poll
      const float* pp = pre + ((size_t)(s * B_ + c)) * G4H + u0 + t;
      p0 = pp[0]; p1 = pp[512]; p2 = pp[1024]; p3 = pp[1536];
    }
    {  // poll own unit's packed {seq|h}
      const unsigned long long* src = hbuf + (((s & 1) * B_ + c) * H_) + t;
      unsigned long long v;
      do {
        v = __hip_atomic_load(src, __ATOMIC_RELAXED, __HIP_MEMORY_SCOPE_AGENT);
      } while ((unsigned)(v >> 32) != (unsigned)s);
      h_lds[t] = __uint_as_float((unsigned)v);
    }
    // wave-local FMA (wave reads only its own lanes' h_lds writes; no sync)
    float a0 = 0.f, a1 = 0.f, a2 = 0.f, a3 = 0.f;
#pragma unroll
    for (int i = 0; i < 32; ++i) {
      float hv = h_lds[k0 + i];
      a0 += wreg[i].x * hv; a1 += wreg[i].y * hv;
      a2 += wreg[i].z * hv; a3 += wreg[i].w * hv;
    }
    *(float4*)&partials[t * 4] = make_float4(a0, a1, a2, a3);
    __syncthreads();  // A: partials ready
    if (t < 128) {
      const int uu = t >> 2, g = t & 3;
      float ssum = 0.f;
#pragma unroll
      for (int q = 0; q < 16; ++q) ssum += partials[(q * 32 + uu) * 4 + g];
      gates_lds[t] = ssum;
    }
    __syncthreads();  // B: gates ready (also orders partials WAR for next step)
    if (is_act) {
      __builtin_amdgcn_s_setprio(1);
      float gi = gates_lds[t * 4 + 0] + p0;
      float gf = gates_lds[t * 4 + 1] + p1;
      float gg = gates_lds[t * 4 + 2] + p2;
      float go = gates_lds[t * 4 + 3] + p3;
      float ig = fsig(gi), fg = fsig(gf);
      float gt = ftanh(gg), og = fsig(go);
      c_state = fg * c_state + ig * gt;
      float h = og * ftanh(c_state);
      // release store FIRST (inter-WG critical path), bookkeeping after
      unsigned long long pk =
          ((unsigned long long)(unsigned)(s + 1) << 32) | (unsigned long long)__float_as_uint(h);
      __hip_atomic_store(hbuf + ((((s + 1) & 1) * B_ + c) * H_) + u0 + t, pk,
                         __ATOMIC_RELAXED, __HIP_MEMORY_SCOPE_AGENT);
      __builtin_amdgcn_s_setprio(0);
      size_t hidx = ((size_t)(s * B_ + c)) * H_ + u0 + t;
      unsigned short hh = f2bf(h);
      hs_hi[hidx] = hh;
      hs_lo[hidx] = f2bf(h - bf2f(hh));
      if (s == S_ - 1) {
        out_tail[c * H_ + u0 + t]            = h;
        out_tail[B_ * H_ + c * H_ + u0 + t]  = c_state;
      }
    }
  }
}

// ---------------------------------------------------------------------------
// K3 (MFMA): out = log_softmax_b(relu(hs @ w_out + b_out)).  (unchanged)
// ---------------------------------------------------------------------------
__global__ __launch_bounds__(256, 2) void k_out(
    const unsigned short* __restrict__ hs_hi, const unsigned short* __restrict__ hs_lo,
    const unsigned short* __restrict__ wT_hi, const unsigned short* __restrict__ wT_lo,
    const float* __restrict__ b_out, float* __restrict__ out)
{
  __shared__ unsigned short lds[4 * 128 * 64];  // A_hi | A_lo | B_hi | B_lo, 64 KB
  char* ldsc = (char*)lds;
  const int t  = threadIdx.x;
  const int w  = t >> 6, l = t & 63;
  const int m0 = blockIdx.x * 128;
  const int n0 = blockIdx.y * 128;
  const int wm = w >> 1, wn = w & 1;
  const int lm = l & 15, lq = l >> 4;

  f32x4 acc[4][4];
#pragma unroll
  for (int fm = 0; fm < 4; ++fm)
#pragma unroll
    for (int fn = 0; fn < 4; ++fn) acc[fm][fn] = (f32x4){0.f, 0.f, 0.f, 0.f};

  for (int kt = 0; kt < H_; kt += 64) {
#pragma unroll
    for (int i = 0; i < 4; ++i) {
      int o   = i * 4096 + w * 1024 + l * 16;
      int r   = o >> 7;
      int c16 = (o >> 4) & 7;
      int cs  = c16 ^ (r & 7);
      const unsigned short* sAh = hs_hi + (size_t)(m0 + r) * 512 + kt + cs * 8;
      const unsigned short* sAl = hs_lo + (size_t)(m0 + r) * 512 + kt + cs * 8;
      const unsigned short* sBh = wT_hi + (size_t)(n0 + r) * 512 + kt + cs * 8;
      const unsigned short* sBl = wT_lo + (size_t)(n0 + r) * 512 + kt + cs * 8;
      GLOAD_LDS16(sAh, ldsc + 0     + i * 4096 + w * 1024);
      GLOAD_LDS16(sAl, ldsc + 16384 + i * 4096 + w * 1024);
      GLOAD_LDS16(sBh, ldsc + 32768 + i * 4096 + w * 1024);
      GLOAD_LDS16(sBl, ldsc + 49152 + i * 4096 + w * 1024);
    }
    __syncthreads();
#pragma unroll
    for (int ks = 0; ks < 2; ++ks) {
      bf16x8 ah[4], al[4], bh[4], bl[4];
#pragma unroll
      for (int f = 0; f < 4; ++f) {
        int ra = wm * 64 + f * 16 + lm;
        int ca = (ks * 4 + lq) ^ (ra & 7);
        ah[f] = *(const bf16x8*)(ldsc + 0     + ra * 128 + ca * 16);
        al[f] = *(const bf16x8*)(ldsc + 16384 + ra * 128 + ca * 16);
        int rb = wn * 64 + f * 16 + lm;
        int cb = (ks * 4 + lq) ^ (rb & 7);
        bh[f] = *(const bf16x8*)(ldsc + 32768 + rb * 128 + cb * 16);
        bl[f] = *(const bf16x8*)(ldsc + 49152 + rb * 128 + cb * 16);
      }
#pragma unroll
      for (int fm = 0; fm < 4; ++fm)
#pragma unroll
        for (int fn = 0; fn < 4; ++fn) {
          acc[fm][fn] = __builtin_amdgcn_mfma_f32_16x16x32_bf16(ah[fm], bh[fn], acc[fm][fn], 0, 0, 0);
          acc[fm][fn] = __builtin_amdgcn_mfma_f32_16x16x32_bf16(ah[fm], bl[fn], acc[fm][fn], 0, 0, 0);
          acc[fm][fn] = __builtin_amdgcn_mfma_f32_16x16x32_bf16(al[fm], bh[fn], acc[fm][fn], 0, 0, 0);
        }
    }
    __syncthreads();
  }

#pragma unroll
  for (int fn = 0; fn < 4; ++fn) {
    const int n = n0 + wn * 64 + fn * 16 + lm;
    const float bo = (n < V_) ? b_out[n] : 0.f;
#pragma unroll
    for (int fm = 0; fm < 4; ++fm) {
      float v[4];
#pragma unroll
      for (int rg = 0; rg < 4; ++rg) v[rg] = fmaxf(acc[fm][fn][rg] + bo, 0.f);
      float mx = fmaxf(fmaxf(v[0], v[1]), fmaxf(v[2], v[3]));
      float gm = fmaxf(mx, __shfl_xor(mx, 16, 64));
      float ss = expf(v[0] - gm) + expf(v[1] - gm) + expf(v[2] - gm) + expf(v[3] - gm);
      float lse = gm + logf(ss + __shfl_xor(ss, 16, 64));
      if (n < V_) {
#pragma unroll
        for (int rg = 0; rg < 4; ++rg) {
          int m = m0 + wm * 64 + fm * 16 + lq * 4 + rg;
          int s = m >> 3, b = m & 7;
          out[(size_t)b * ((size_t)S_ * V_) + (size_t)s * V_ + n] = v[rg] - lse;
        }
      }
    }
  }
}

// ---------------------------------------------------------------------------
extern "C" void kernel_launch(void* const* d_in, const int* in_sizes, int n_in,
                              void* d_out, int out_size, void* d_ws, size_t ws_size,
                              hipStream_t stream) {
  const int*   tokens = (const int*)d_in[0];
  const float* embed  = (const float*)d_in[1];
  const float* w_ih   = (const float*)d_in[2];
  const float* w_hh   = (const float*)d_in[3];
  const float* bias   = (const float*)d_in[4];
  const float* w_out  = (const float*)d_in[5];
  const float* b_out  = (const float*)d_in[6];
  float* out = (float*)d_out;

  char* ws = (char*)d_ws;
  float*              pre   = (float*)(ws);                         // 33,554,432 B
  unsigned short*     hs_hi = (unsigned short*)(ws + 33554432);     //  4,194,304 B
  unsigned short*     hs_lo = (unsigned short*)(ws + 37748736);     //  4,194,304 B
  unsigned short*     wT_hi = (unsigned short*)(ws + 41943040);     // 10,354,688 B
  unsigned short*     wT_lo = (unsigned short*)(ws + 52297728);     // 10,354,688 B
  unsigned long long* hbuf  = (unsigned long long*)(ws + 62652416); //     65,536 B

  hipMemsetAsync(hbuf, 0, 2 * B_ * H_ * sizeof(unsigned long long), stream);

  k_wconv<<<dim3(158, 8), 256, 0, stream>>>(w_out, wT_hi, wT_lo);
  k_pre<<<dim3(64, 32), 256, 0, stream>>>(tokens, embed, w_ih, bias, pre);
  k_rec<<<dim3(128), 512, 0, stream>>>(pre, w_hh, hbuf, hs_hi, hs_lo,
                                       out + (size_t)B_ * S_ * V_);
  k_out<<<dim3(32, 79), 256, 0, stream>>>(hs_hi, hs_lo, wT_hi, wT_lo, b_out, out);
}

// Round 7
// 1046.128 us; speedup vs baseline: 1.6565x; 1.0503x over previous
//
#include <hip/hip_runtime.h>
#include <math.h>

#define V_  10000
#define E_  256
#define H_  512
#define B_  8
#define S_  512
#define G4H 2048   // 4*H
#define NPAD 10112 // 79*128, padded N for k_out

typedef __attribute__((ext_vector_type(8))) short bf16x8;
typedef __attribute__((ext_vector_type(4))) float f32x4;

__device__ __forceinline__ unsigned short f2bf(float x) {
  unsigned u = __float_as_uint(x);
  return (unsigned short)((u + 0x7fffu + ((u >> 16) & 1u)) >> 16);
}
__device__ __forceinline__ float bf2f(unsigned short h) {
  return __uint_as_float(((unsigned)h) << 16);
}
// fast activations on the serial critical path (clamped; exact at saturation)
__device__ __forceinline__ float fsig(float x) {
  x = fminf(fmaxf(x, -30.f), 30.f);
  return __builtin_amdgcn_rcpf(1.f + __builtin_amdgcn_exp2f(-1.44269504f * x));
}
__device__ __forceinline__ float ftanh(float x) {
  x = fminf(fmaxf(x, -9.f), 9.f);
  float E = __builtin_amdgcn_exp2f(2.88539008f * x);  // e^{2x}
  return (E - 1.f) * __builtin_amdgcn_rcpf(E + 1.f);
}

#define GLOAD_LDS16(gsrc, ldst)                                                       \
  __builtin_amdgcn_global_load_lds((const __attribute__((address_space(1))) unsigned*)(gsrc), \
                                   (__attribute__((address_space(3))) unsigned*)(ldst), 16, 0, 0)

// ---------------------------------------------------------------------------
// K1: pre[m][j] = embed[tok(m)][:] @ w_ih[:, j] + bias[j],  m = s*8+b  (fp32)
// ---------------------------------------------------------------------------
__global__ __launch_bounds__(256, 4) void k_pre(
    const int* __restrict__ tokens, const float* __restrict__ embed,
    const float* __restrict__ w_ih, const float* __restrict__ bias,
    float* __restrict__ pre)
{
  __shared__ float A_lds[64 * 36];
  __shared__ float B_lds[32 * 64];
  __shared__ int   tok_lds[64];
  const int t  = threadIdx.x;
  const int m0 = blockIdx.x * 64;
  const int j0 = blockIdx.y * 64;
  if (t < 64) {
    int m = m0 + t;
    int s = m >> 3, b = m & 7;
    tok_lds[t] = tokens[b * S_ + s];
  }
  __syncthreads();
  const int tx = t & 15, ty = t >> 4;
  const int r_st = t >> 2, q_st = t & 3;
  const int kk_st = t >> 3, q2_st = t & 7;
  float acc[4][4] = {};
  for (int kt = 0; kt < E_; kt += 32) {
    {
      int tok = tok_lds[r_st];
      const float4* src = (const float4*)(embed + (size_t)tok * E_ + kt);
      float4 v0 = src[q_st];
      float4 v1 = src[q_st + 4];
      *(float4*)&A_lds[r_st * 36 + q_st * 4]       = v0;
      *(float4*)&A_lds[r_st * 36 + (q_st + 4) * 4] = v1;
    }
    {
      const float4* src = (const float4*)(w_ih + (size_t)(kt + kk_st) * G4H + j0);
      float4 v0 = src[q2_st];
      float4 v1 = src[q2_st + 8];
      *(float4*)&B_lds[kk_st * 64 + q2_st * 4]       = v0;
      *(float4*)&B_lds[kk_st * 64 + (q2_st + 8) * 4] = v1;
    }
    __syncthreads();
#pragma unroll
    for (int kkg = 0; kkg < 8; ++kkg) {
      float a_[4][4], b_[4][4];
#pragma unroll
      for (int i = 0; i < 4; ++i) {
        float4 av = *(const float4*)&A_lds[(ty * 4 + i) * 36 + kkg * 4];
        a_[i][0] = av.x; a_[i][1] = av.y; a_[i][2] = av.z; a_[i][3] = av.w;
      }
#pragma unroll
      for (int dk = 0; dk < 4; ++dk) {
        float4 bv = *(const float4*)&B_lds[(kkg * 4 + dk) * 64 + tx * 4];
        b_[dk][0] = bv.x; b_[dk][1] = bv.y; b_[dk][2] = bv.z; b_[dk][3] = bv.w;
      }
#pragma unroll
      for (int i = 0; i < 4; ++i)
#pragma unroll
        for (int dk = 0; dk < 4; ++dk)
#pragma unroll
          for (int j = 0; j < 4; ++j)
            acc[i][j] += a_[i][dk] * b_[dk][j];
    }
    __syncthreads();
  }
  const int j = j0 + tx * 4;
  float4 bi = *(const float4*)(bias + j);
#pragma unroll
  for (int i = 0; i < 4; ++i) {
    int m = m0 + ty * 4 + i;
    float4 o;
    o.x = acc[i][0] + bi.x; o.y = acc[i][1] + bi.y;
    o.z = acc[i][2] + bi.z; o.w = acc[i][3] + bi.w;
    *(float4*)&pre[(size_t)m * G4H + j] = o;
  }
}

// ---------------------------------------------------------------------------
// K-conv: w_out [512][10000] fp32 -> transposed bf16 hi/lo [NPAD][512].
// ---------------------------------------------------------------------------
__global__ __launch_bounds__(256, 4) void k_wconv(
    const float* __restrict__ w_out,
    unsigned short* __restrict__ wT_hi, unsigned short* __restrict__ wT_lo)
{
  __shared__ float tile[64][65];
  const int t  = threadIdx.x;
  const int n0 = blockIdx.x * 64;
  const int k0 = blockIdx.y * 64;
  const int cn = (t & 15) * 4, rk = t >> 4;
#pragma unroll
  for (int p = 0; p < 4; ++p) {
    int k = k0 + rk + p * 16;
    int n = n0 + cn;
    float v[4];
    if (n + 3 < V_) {
      float4 x = *(const float4*)(w_out + (size_t)k * V_ + n);
      v[0] = x.x; v[1] = x.y; v[2] = x.z; v[3] = x.w;
    } else {
#pragma unroll
      for (int j = 0; j < 4; ++j) v[j] = (n + j < V_) ? w_out[(size_t)k * V_ + n + j] : 0.f;
    }
#pragma unroll
    for (int j = 0; j < 4; ++j) tile[rk + p * 16][cn + j] = v[j];
  }
  __syncthreads();
  const int n_l = t >> 2, kq = t & 3;
  unsigned short hib[16], lob[16];
#pragma unroll
  for (int j = 0; j < 16; ++j) {
    float x = tile[kq * 16 + j][n_l];
    unsigned short h = f2bf(x);
    hib[j] = h;
    lob[j] = f2bf(x - bf2f(h));
  }
  size_t base = (size_t)(n0 + n_l) * 512 + k0 + kq * 16;
#pragma unroll
  for (int q = 0; q < 4; ++q) {
    *(ushort4*)&wT_hi[base + q * 4] = *(ushort4*)&hib[q * 4];
    *(ushort4*)&wT_lo[base + q * 4] = *(ushort4*)&lob[q * 4];
  }
}

// ---------------------------------------------------------------------------
// K2: round-6 structure (744 us known-good) with ONE change: XCD-local
// clusters (c = bid&7, r = bid>>3) — all 16 WGs of batch c on XCD c under
// default round-robin block->XCD. Tests whether the agent-scope atomic
// h-exchange gets serviced in the XCD's L2 (R4 evidence: FETCH halved).
// ---------------------------------------------------------------------------
__global__ __launch_bounds__(512, 2) void k_rec(
    const float* __restrict__ pre, const float* __restrict__ w_hh,
    unsigned long long* __restrict__ hbuf,  // [2][B][H] u64, zeroed
    unsigned short* __restrict__ hs_hi,     // [S*B][H] bf16
    unsigned short* __restrict__ hs_lo,     // [S*B][H] bf16
    float* __restrict__ out_tail)           // h_T [B][H] then c_T [B][H]
{
  __shared__ float h_lds[H_];
  __shared__ float partials[16 * 32 * 4];
  __shared__ float gates_lds[32 * 4];

  const int t   = threadIdx.x;
  const int bid = blockIdx.x;
  const int c   = bid & 7;    // batch/cluster: XCD-local (ONLY change vs R6)
  const int r   = bid >> 3;   // rank within cluster
  const int u0  = r * 32;
  const int u_l = t & 31;
  const int kq  = t >> 5;
  const int k0  = kq * 32;
  const int ug  = u0 + u_l;

  float4 wreg[32];
#pragma unroll
  for (int i = 0; i < 32; ++i) {
    const float* wr = w_hh + (size_t)(k0 + i) * G4H + ug;
    wreg[i] = make_float4(wr[0], wr[512], wr[1024], wr[1536]);
  }

  const bool is_act = (t < 32);
  float c_state = 0.f;

  for (int s = 0; s < S_; ++s) {
    float p0 = 0.f, p1 = 0.f, p2 = 0.f, p3 = 0.f;
    if (is_act) {  // prefetch pre, overlaps the poll
      const float* pp = pre + ((size_t)(s * B_ + c)) * G4H + u0 + t;
      p0 = pp[0]; p1 = pp[512]; p2 = pp[1024]; p3 = pp[1536];
    }
    {  // poll own unit's packed {seq|h}
      const unsigned long long* src = hbuf + (((s & 1) * B_ + c) * H_) + t;
      unsigned long long v;
      do {
        v = __hip_atomic_load(src, __ATOMIC_RELAXED, __HIP_MEMORY_SCOPE_AGENT);
      } while ((unsigned)(v >> 32) != (unsigned)s);
      h_lds[t] = __uint_as_float((unsigned)v);
    }
    // wave-local FMA (wave reads only its own lanes' h_lds writes; no sync)
    float a0 = 0.f, a1 = 0.f, a2 = 0.f, a3 = 0.f;
#pragma unroll
    for (int i = 0; i < 32; ++i) {
      float hv = h_lds[k0 + i];
      a0 += wreg[i].x * hv; a1 += wreg[i].y * hv;
      a2 += wreg[i].z * hv; a3 += wreg[i].w * hv;
    }
    *(float4*)&partials[t * 4] = make_float4(a0, a1, a2, a3);
    __syncthreads();  // A: partials ready
    if (t < 128) {
      const int uu = t >> 2, g = t & 3;
      float ssum = 0.f;
#pragma unroll
      for (int q = 0; q < 16; ++q) ssum += partials[(q * 32 + uu) * 4 + g];
      gates_lds[t] = ssum;
    }
    __syncthreads();  // B: gates ready (also orders partials WAR for next step)
    if (is_act) {
      __builtin_amdgcn_s_setprio(1);
      float gi = gates_lds[t * 4 + 0] + p0;
      float gf = gates_lds[t * 4 + 1] + p1;
      float gg = gates_lds[t * 4 + 2] + p2;
      float go = gates_lds[t * 4 + 3] + p3;
      float ig = fsig(gi), fg = fsig(gf);
      float gt = ftanh(gg), og = fsig(go);
      c_state = fg * c_state + ig * gt;
      float h = og * ftanh(c_state);
      // release store FIRST (inter-WG critical path), bookkeeping after
      unsigned long long pk =
          ((unsigned long long)(unsigned)(s + 1) << 32) | (unsigned long long)__float_as_uint(h);
      __hip_atomic_store(hbuf + ((((s + 1) & 1) * B_ + c) * H_) + u0 + t, pk,
                         __ATOMIC_RELAXED, __HIP_MEMORY_SCOPE_AGENT);
      __builtin_amdgcn_s_setprio(0);
      size_t hidx = ((size_t)(s * B_ + c)) * H_ + u0 + t;
      unsigned short hh = f2bf(h);
      hs_hi[hidx] = hh;
      hs_lo[hidx] = f2bf(h - bf2f(hh));
      if (s == S_ - 1) {
        out_tail[c * H_ + u0 + t]            = h;
        out_tail[B_ * H_ + c * H_ + u0 + t]  = c_state;
      }
    }
  }
}

// ---------------------------------------------------------------------------
// K3 (MFMA): out = log_softmax_b(relu(hs @ w_out + b_out)).  (unchanged)
// ---------------------------------------------------------------------------
__global__ __launch_bounds__(256, 2) void k_out(
    const unsigned short* __restrict__ hs_hi, const unsigned short* __restrict__ hs_lo,
    const unsigned short* __restrict__ wT_hi, const unsigned short* __restrict__ wT_lo,
    const float* __restrict__ b_out, float* __restrict__ out)
{
  __shared__ unsigned short lds[4 * 128 * 64];  // A_hi | A_lo | B_hi | B_lo, 64 KB
  char* ldsc = (char*)lds;
  const int t  = threadIdx.x;
  const int w  = t >> 6, l = t & 63;
  const int m0 = blockIdx.x * 128;
  const int n0 = blockIdx.y * 128;
  const int wm = w >> 1, wn = w & 1;
  const int lm = l & 15, lq = l >> 4;

  f32x4 acc[4][4];
#pragma unroll
  for (int fm = 0; fm < 4; ++fm)
#pragma unroll
    for (int fn = 0; fn < 4; ++fn) acc[fm][fn] = (f32x4){0.f, 0.f, 0.f, 0.f};

  for (int kt = 0; kt < H_; kt += 64) {
#pragma unroll
    for (int i = 0; i < 4; ++i) {
      int o   = i * 4096 + w * 1024 + l * 16;
      int r   = o >> 7;
      int c16 = (o >> 4) & 7;
      int cs  = c16 ^ (r & 7);
      const unsigned short* sAh = hs_hi + (size_t)(m0 + r) * 512 + kt + cs * 8;
      const unsigned short* sAl = hs_lo + (size_t)(m0 + r) * 512 + kt + cs * 8;
      const unsigned short* sBh = wT_hi + (size_t)(n0 + r) * 512 + kt + cs * 8;
      const unsigned short* sBl = wT_lo + (size_t)(n0 + r) * 512 + kt + cs * 8;
      GLOAD_LDS16(sAh, ldsc + 0     + i * 4096 + w * 1024);
      GLOAD_LDS16(sAl, ldsc + 16384 + i * 4096 + w * 1024);
      GLOAD_LDS16(sBh, ldsc + 32768 + i * 4096 + w * 1024);
      GLOAD_LDS16(sBl, ldsc + 49152 + i * 4096 + w * 1024);
    }
    __syncthreads();
#pragma unroll
    for (int ks = 0; ks < 2; ++ks) {
      bf16x8 ah[4], al[4], bh[4], bl[4];
#pragma unroll
      for (int f = 0; f < 4; ++f) {
        int ra = wm * 64 + f * 16 + lm;
        int ca = (ks * 4 + lq) ^ (ra & 7);
        ah[f] = *(const bf16x8*)(ldsc + 0     + ra * 128 + ca * 16);
        al[f] = *(const bf16x8*)(ldsc + 16384 + ra * 128 + ca * 16);
        int rb = wn * 64 + f * 16 + lm;
        int cb = (ks * 4 + lq) ^ (rb & 7);
        bh[f] = *(const bf16x8*)(ldsc + 32768 + rb * 128 + cb * 16);
        bl[f] = *(const bf16x8*)(ldsc + 49152 + rb * 128 + cb * 16);
      }
#pragma unroll
      for (int fm = 0; fm < 4; ++fm)
#pragma unroll
        for (int fn = 0; fn < 4; ++fn) {
          acc[fm][fn] = __builtin_amdgcn_mfma_f32_16x16x32_bf16(ah[fm], bh[fn], acc[fm][fn], 0, 0, 0);
          acc[fm][fn] = __builtin_amdgcn_mfma_f32_16x16x32_bf16(ah[fm], bl[fn], acc[fm][fn], 0, 0, 0);
          acc[fm][fn] = __builtin_amdgcn_mfma_f32_16x16x32_bf16(al[fm], bh[fn], acc[fm][fn], 0, 0, 0);
        }
    }
    __syncthreads();
  }

#pragma unroll
  for (int fn = 0; fn < 4; ++fn) {
    const int n = n0 + wn * 64 + fn * 16 + lm;
    const float bo = (n < V_) ? b_out[n] : 0.f;
#pragma unroll
    for (int fm = 0; fm < 4; ++fm) {
      float v[4];
#pragma unroll
      for (int rg = 0; rg < 4; ++rg) v[rg] = fmaxf(acc[fm][fn][rg] + bo, 0.f);
      float mx = fmaxf(fmaxf(v[0], v[1]), fmaxf(v[2], v[3]));
      float gm = fmaxf(mx, __shfl_xor(mx, 16, 64));
      float ss = expf(v[0] - gm) + expf(v[1] - gm) + expf(v[2] - gm) + expf(v[3] - gm);
      float lse = gm + logf(ss + __shfl_xor(ss, 16, 64));
      if (n < V_) {
#pragma unroll
        for (int rg = 0; rg < 4; ++rg) {
          int m = m0 + wm * 64 + fm * 16 + lq * 4 + rg;
          int s = m >> 3, b = m & 7;
          out[(size_t)b * ((size_t)S_ * V_) + (size_t)s * V_ + n] = v[rg] - lse;
        }
      }
    }
  }
}

// ---------------------------------------------------------------------------
extern "C" void kernel_launch(void* const* d_in, const int* in_sizes, int n_in,
                              void* d_out, int out_size, void* d_ws, size_t ws_size,
                              hipStream_t stream) {
  const int*   tokens = (const int*)d_in[0];
  const float* embed  = (const float*)d_in[1];
  const float* w_ih   = (const float*)d_in[2];
  const float* w_hh   = (const float*)d_in[3];
  const float* bias   = (const float*)d_in[4];
  const float* w_out  = (const float*)d_in[5];
  const float* b_out  = (const float*)d_in[6];
  float* out = (float*)d_out;

  char* ws = (char*)d_ws;
  float*              pre   = (float*)(ws);                         // 33,554,432 B
  unsigned short*     hs_hi = (unsigned short*)(ws + 33554432);     //  4,194,304 B
  unsigned short*     hs_lo = (unsigned short*)(ws + 37748736);     //  4,194,304 B
  unsigned short*     wT_hi = (unsigned short*)(ws + 41943040);     // 10,354,688 B
  unsigned short*     wT_lo = (unsigned short*)(ws + 52297728);     // 10,354,688 B
  unsigned long long* hbuf  = (unsigned long long*)(ws + 62652416); //     65,536 B

  hipMemsetAsync(hbuf, 0, 2 * B_ * H_ * sizeof(unsigned long long), stream);

  k_wconv<<<dim3(158, 8), 256, 0, stream>>>(w_out, wT_hi, wT_lo);
  k_pre<<<dim3(64, 32), 256, 0, stream>>>(tokens, embed, w_ih, bias, pre);
  k_rec<<<dim3(128), 512, 0, stream>>>(pre, w_hh, hbuf, hs_hi, hs_lo,
                                       out + (size_t)B_ * S_ * V_);
  k_out<<<dim3(32, 79), 256, 0, stream>>>(hs_hi, hs_lo, wT_hi, wT_lo, b_out, out);
}